// Round 20
// baseline (191.816 us; speedup 1.0000x reference)
//
#include <hip/hip_runtime.h>
#include <stdint.h>

#define DIMD 1024
#define HEADS 16
#define HD 64
#define SEQ 2048
#define BATCH 2
#define MTOT (BATCH*SEQ)   // 4096

typedef __attribute__((ext_vector_type(4))) float f32x4;
typedef __attribute__((ext_vector_type(8))) short bf16x8;      // 8 bf16 in 4 VGPRs (MFMA A/B frag)
typedef __attribute__((ext_vector_type(8))) unsigned short ushort8;
typedef __attribute__((ext_vector_type(4))) unsigned short usx4;   // 'ushort4' collides with HIP types

// async global->LDS, 16B per lane; LDS dest must be wave-uniform base + lane*16 (linear)
#define GL_LDS16(gp, lp) __builtin_amdgcn_global_load_lds( \
    (const __attribute__((address_space(1))) unsigned int*)(gp), \
    (__attribute__((address_space(3))) unsigned int*)(lp), 16, 0, 0)

__device__ __forceinline__ unsigned short f2bf(float f) {
    unsigned int u = __builtin_bit_cast(unsigned int, f);
    u = (u + 0x7FFFu + ((u >> 16) & 1u)) >> 16;   // round-to-nearest-even
    return (unsigned short)u;
}
__device__ __forceinline__ float bf2f(unsigned short s) {
    unsigned int u = ((unsigned int)s) << 16;
    return __builtin_bit_cast(float, u);
}

// ---------------- fp32 -> bf16 convert (8 elems/thread) ----------------
__global__ __launch_bounds__(256) void cvt_f32_bf16(const float* __restrict__ in,
                                                    unsigned short* __restrict__ out, int n) {
    int i = (blockIdx.x * 256 + threadIdx.x) * 8;
    if (i >= n) return;
    f32x4 a = *(const f32x4*)(in + i);
    f32x4 b = *(const f32x4*)(in + i + 4);
    ushort8 o;
    o[0] = f2bf(a[0]); o[1] = f2bf(a[1]); o[2] = f2bf(a[2]); o[3] = f2bf(a[3]);
    o[4] = f2bf(b[0]); o[5] = f2bf(b[1]); o[6] = f2bf(b[2]); o[7] = f2bf(b[3]);
    *(ushort8*)(out + i) = o;
}

// all 4 weight matrices in one launch (dsts are contiguous in ws)
__global__ __launch_bounds__(256) void cvt_w4(const float* __restrict__ w0, const float* __restrict__ w1,
                                              const float* __restrict__ w2, const float* __restrict__ w3,
                                              unsigned short* __restrict__ dst) {
    const int sel = blockIdx.x >> 9;
    const float* src = sel == 0 ? w0 : sel == 1 ? w1 : sel == 2 ? w2 : w3;
    int i = ((blockIdx.x & 511) * 256 + threadIdx.x) * 8;
    f32x4 a = *(const f32x4*)(src + i);
    f32x4 b = *(const f32x4*)(src + i + 4);
    ushort8 o;
    o[0] = f2bf(a[0]); o[1] = f2bf(a[1]); o[2] = f2bf(a[2]); o[3] = f2bf(a[3]);
    o[4] = f2bf(b[0]); o[5] = f2bf(b[1]); o[6] = f2bf(b[2]); o[7] = f2bf(b[3]);
    *(ushort8*)(dst + (size_t)sel * 1048576 + i) = o;
}

// ---------------- LDS-staged GEMM body (tile 128Mx64N, BK=64, dbuf, XOR-swz) ----------
template<bool F32OUT>
__device__ __forceinline__ void gemm_body(const unsigned short* __restrict__ X,
                                          const unsigned short* __restrict__ W,
                                          const float* __restrict__ bias,
                                          void* __restrict__ outp,
                                          int m0, int n0, int Nv, int Kv,
                                          unsigned short (*As)[128 * 64],
                                          unsigned short (*Bs)[64 * 64]) {
    const int tid = threadIdx.x, wid = tid >> 6;
    const int lane = tid & 63, lr = lane & 15, hi = lane >> 4;
    const int mq = (wid >> 1) * 64, nq = (wid & 1) * 32;
    const int NT = Kv >> 6;

    f32x4 acc[4][2];
    #pragma unroll
    for (int i = 0; i < 4; ++i)
        #pragma unroll
        for (int j = 0; j < 2; ++j) acc[i][j] = (f32x4){0.f, 0.f, 0.f, 0.f};

    #pragma unroll
    for (int it = 0; it < 4; ++it) {
        int li = it * 256 + tid, row = li >> 3, seg = li & 7;
        GL_LDS16(X + (size_t)(m0 + row) * Kv + ((seg ^ (row & 7)) << 3), &As[0][li * 8]);
    }
    #pragma unroll
    for (int it = 0; it < 2; ++it) {
        int li = it * 256 + tid, row = li >> 3, seg = li & 7;
        GL_LDS16(W + (size_t)(n0 + row) * Kv + ((seg ^ (row & 7)) << 3), &Bs[0][li * 8]);
    }
    __syncthreads();

    #pragma unroll 2
    for (int t = 0; t < NT; ++t) {
        const int cur = t & 1, nxt = cur ^ 1;
        if (t + 1 < NT) {
            const int k1 = (t + 1) << 6;
            #pragma unroll
            for (int it = 0; it < 4; ++it) {
                int li = it * 256 + tid, row = li >> 3, seg = li & 7;
                GL_LDS16(X + (size_t)(m0 + row) * Kv + k1 + ((seg ^ (row & 7)) << 3),
                         &As[nxt][li * 8]);
            }
            #pragma unroll
            for (int it = 0; it < 2; ++it) {
                int li = it * 256 + tid, row = li >> 3, seg = li & 7;
                GL_LDS16(W + (size_t)(n0 + row) * Kv + k1 + ((seg ^ (row & 7)) << 3),
                         &Bs[nxt][li * 8]);
            }
        }
        #pragma unroll
        for (int kk = 0; kk < 2; ++kk) {
            bf16x8 af[4], bfr[2];
            #pragma unroll
            for (int i = 0; i < 4; ++i) {
                int row = mq + 16 * i + lr;
                int seg = (kk * 4 + hi) ^ (row & 7);
                af[i] = *(const bf16x8*)(&As[cur][row * 64 + seg * 8]);
            }
            #pragma unroll
            for (int j = 0; j < 2; ++j) {
                int row = nq + 16 * j + lr;
                int seg = (kk * 4 + hi) ^ (row & 7);
                bfr[j] = *(const bf16x8*)(&Bs[cur][row * 64 + seg * 8]);
            }
            #pragma unroll
            for (int i = 0; i < 4; ++i)
                #pragma unroll
                for (int j = 0; j < 2; ++j)
                    acc[i][j] = __builtin_amdgcn_mfma_f32_16x16x32_bf16(af[i], bfr[j], acc[i][j], 0, 0, 0);
        }
        __syncthreads();
    }

    #pragma unroll
    for (int j = 0; j < 2; ++j) {
        const int col = n0 + nq + 16 * j + lr;
        const float bv = bias[col];
        #pragma unroll
        for (int i = 0; i < 4; ++i) {
            #pragma unroll
            for (int r = 0; r < 4; ++r) {
                const int row = m0 + mq + 16 * i + 4 * hi + r;
                float v = acc[i][j][r] + bv;
                if (F32OUT) ((float*)outp)[(size_t)row * Nv + col] = v;
                else        ((unsigned short*)outp)[(size_t)row * Nv + col] = f2bf(v);
            }
        }
    }
}

template<bool F32OUT>
__global__ __launch_bounds__(256, 2) void gemm_lds(const unsigned short* __restrict__ X,
                                                   const unsigned short* __restrict__ W,
                                                   const float* __restrict__ bias,
                                                   void* __restrict__ outp,
                                                   int Nv, int Kv) {
    __shared__ unsigned short As[2][128 * 64];
    __shared__ unsigned short Bs[2][64 * 64];
    gemm_body<F32OUT>(X, W, bias, outp, blockIdx.y * 128, blockIdx.x * 64, Nv, Kv, As, Bs);
}

// ---------------- gemm_qkv v2: 128M x 128N tile (32 MFMA/step vs 16) ----------------
// Q/K/V projections in one dispatch. Tile 128x128, BK=64, dbuf, XOR-swz; 4 waves
// (2M x 2N, wave tile 64x64, acc[4][4]); LDS 64 KB -> 2 blocks/CU. Per guide's
// tile-space data (64p=343, 128p=912 TF at this structure) the wider tile halves
// per-MFMA overhead + B-operand global traffic. grid (3 sels x 8 ntiles, 32).
__global__ __launch_bounds__(256, 2) void gemm_qkv(const unsigned short* __restrict__ X,
                                                   const unsigned short* __restrict__ Wall,
                                                   const float* __restrict__ b0,
                                                   const float* __restrict__ b1,
                                                   const float* __restrict__ b2,
                                                   unsigned short* __restrict__ o0,
                                                   unsigned short* __restrict__ o1,
                                                   unsigned short* __restrict__ o2) {
    __shared__ unsigned short As[2][128 * 64];   // 16 KB each
    __shared__ unsigned short Bs[2][128 * 64];   // 16 KB each
    const int sel = blockIdx.x >> 3;
    const int n0 = (blockIdx.x & 7) * 128;
    const unsigned short* W = Wall + (size_t)sel * 1048576;
    const float* bias = sel == 0 ? b0 : sel == 1 ? b1 : b2;
    unsigned short* out = sel == 0 ? o0 : sel == 1 ? o1 : o2;

    const int tid = threadIdx.x, wid = tid >> 6;
    const int lane = tid & 63, lr = lane & 15, hi = lane >> 4;
    const int m0 = blockIdx.y * 128;
    const int mq = (wid >> 1) * 64, nq = (wid & 1) * 64;

    f32x4 acc[4][4];
    #pragma unroll
    for (int i = 0; i < 4; ++i)
        #pragma unroll
        for (int j = 0; j < 4; ++j) acc[i][j] = (f32x4){0.f, 0.f, 0.f, 0.f};

    #pragma unroll
    for (int it = 0; it < 4; ++it) {
        int li = it * 256 + tid, row = li >> 3, seg = li & 7;
        GL_LDS16(X + (size_t)(m0 + row) * DIMD + ((seg ^ (row & 7)) << 3), &As[0][li * 8]);
    }
    #pragma unroll
    for (int it = 0; it < 4; ++it) {
        int li = it * 256 + tid, row = li >> 3, seg = li & 7;
        GL_LDS16(W + (size_t)(n0 + row) * DIMD + ((seg ^ (row & 7)) << 3), &Bs[0][li * 8]);
    }
    __syncthreads();

    #pragma unroll 2
    for (int t = 0; t < 16; ++t) {               // 1024/64 K-steps
        const int cur = t & 1, nxt = cur ^ 1;
        if (t + 1 < 16) {
            const int k1 = (t + 1) << 6;
            #pragma unroll
            for (int it = 0; it < 4; ++it) {
                int li = it * 256 + tid, row = li >> 3, seg = li & 7;
                GL_LDS16(X + (size_t)(m0 + row) * DIMD + k1 + ((seg ^ (row & 7)) << 3),
                         &As[nxt][li * 8]);
            }
            #pragma unroll
            for (int it = 0; it < 4; ++it) {
                int li = it * 256 + tid, row = li >> 3, seg = li & 7;
                GL_LDS16(W + (size_t)(n0 + row) * DIMD + k1 + ((seg ^ (row & 7)) << 3),
                         &Bs[nxt][li * 8]);
            }
        }
        #pragma unroll
        for (int kk = 0; kk < 2; ++kk) {
            bf16x8 af[4], bfr[4];
            #pragma unroll
            for (int i = 0; i < 4; ++i) {
                int row = mq + 16 * i + lr;
                int seg = (kk * 4 + hi) ^ (row & 7);
                af[i] = *(const bf16x8*)(&As[cur][row * 64 + seg * 8]);
            }
            #pragma unroll
            for (int j = 0; j < 4; ++j) {
                int row = nq + 16 * j + lr;
                int seg = (kk * 4 + hi) ^ (row & 7);
                bfr[j] = *(const bf16x8*)(&Bs[cur][row * 64 + seg * 8]);
            }
            #pragma unroll
            for (int i = 0; i < 4; ++i)
                #pragma unroll
                for (int j = 0; j < 4; ++j)
                    acc[i][j] = __builtin_amdgcn_mfma_f32_16x16x32_bf16(af[i], bfr[j], acc[i][j], 0, 0, 0);
        }
        __syncthreads();
    }

    #pragma unroll
    for (int j = 0; j < 4; ++j) {
        const int col = n0 + nq + 16 * j + lr;
        const float bv = bias[col];
        #pragma unroll
        for (int i = 0; i < 4; ++i) {
            #pragma unroll
            for (int r = 0; r < 4; ++r) {
                const int row = m0 + mq + 16 * i + 4 * hi + r;
                out[(size_t)row * DIMD + col] = f2bf(acc[i][j][r] + bv);
            }
        }
    }
}

// ---------------- V transpose: v[b,s,h*64+d] -> vT[(b*H+h)*64+d][s] ----------------
__global__ __launch_bounds__(256) void transpose_v(const unsigned short* __restrict__ v,
                                                   unsigned short* __restrict__ vT) {
    __shared__ unsigned short tile[64][72];
    const int bh = blockIdx.y;
    const int b = bh >> 4, h = bh & 15;
    const int s0 = blockIdx.x * 64;
    const int t = threadIdx.x;
    #pragma unroll
    for (int it = 0; it < 2; ++it) {
        int li = it * 256 + t;
        int row = li >> 3, c8 = (li & 7) * 8;
        ushort8 val = *(const ushort8*)(v + (size_t)(b * SEQ + s0 + row) * DIMD + h * HD + c8);
        *(ushort8*)&tile[row][c8] = val;
    }
    __syncthreads();
    #pragma unroll
    for (int it = 0; it < 2; ++it) {
        int li = it * 256 + t;
        int d = li >> 3, s8 = (li & 7) * 8;
        ushort8 o;
        #pragma unroll
        for (int j = 0; j < 8; ++j) o[j] = tile[s8 + j][d];
        *(ushort8*)(vT + (size_t)(bh * HD + d) * SEQ + s0 + s8) = o;
    }
}

// ---------------- fused score+PV (round-16 BEST-KNOWN config) --------------
// 32 q-rows per block, 4 waves, grid(64,16,2) -> 2048 blocks, 4 blocks/CU resident.
// Per 64-k step: prefetch K/V (dbuf, XOR-swz) | QK^T (swapped: A=K rows, D row=k
// col=q) -> __expf -> f2bf(RNE) -> Es | bar1 (lgkmcnt-only) | PV from Es,Vs | bar2.
// A/B history: +setprio = +4.3% (r17); wave-private single-barrier = +14% (r15);
// 64q blocks = occupancy loss (r10). This structure measured best: 82.6 us.
__global__ __launch_bounds__(256, 4) void score_pv_kernel(const unsigned short* __restrict__ Q,
                                                          const unsigned short* __restrict__ Kt,
                                                          const unsigned short* __restrict__ vT,
                                                          float* __restrict__ rlb_all,
                                                          unsigned short* __restrict__ attn) {
    __shared__ unsigned short Ks[2][64 * 64];    // 8 KB each
    __shared__ unsigned short Vs[2][64 * 64];    // 8 KB each
    __shared__ unsigned short Es[32 * 68];       // 4.25 KB, pitch 68 -> bank-spread
    __shared__ float ps[4][2][16];
    __shared__ float rls[32];
    const int tid = threadIdx.x, wid = tid >> 6, lane = tid & 63;
    const int lr = lane & 15, hi = lane >> 4;
    const int h = blockIdx.y;
    const int b = blockIdx.z;
    const int q0 = blockIdx.x * 32;
    float* rlb = rlb_all + (size_t)b * HEADS * SEQ;
    const unsigned short* Kbase = Kt + (size_t)b * SEQ * DIMD + h * HD;
    const unsigned short* Vbase = vT + (size_t)(b * HEADS + h) * HD * SEQ;

    const unsigned short* qbase = Q + (size_t)(b * SEQ + q0) * DIMD + h * HD + 8 * hi;
    bf16x8 qb0[2], qb1[2];
    #pragma unroll
    for (int s = 0; s < 2; ++s) {
        const unsigned short* qp = qbase + (size_t)(16 * s + lr) * DIMD;
        qb0[s] = *(const bf16x8*)qp;
        qb1[s] = *(const bf16x8*)(qp + 32);
    }

    #pragma unroll
    for (int it = 0; it < 2; ++it) {
        int li = it * 256 + tid, row = li >> 3, seg = li & 7;
        GL_LDS16(Kbase + (size_t)row * DIMD + ((seg ^ (row & 7)) << 3), &Ks[0][li * 8]);
    }
    #pragma unroll
    for (int it = 0; it < 2; ++it) {
        int li = it * 256 + tid, row = li >> 3, seg = li & 7;
        GL_LDS16(Vbase + (size_t)row * SEQ + ((seg ^ (row & 7)) << 3), &Vs[0][li * 8]);
    }
    __syncthreads();

    float lsum[2] = {0.f, 0.f};
    f32x4 oacc[2];
    oacc[0] = (f32x4){0.f, 0.f, 0.f, 0.f};
    oacc[1] = (f32x4){0.f, 0.f, 0.f, 0.f};
    const int mq = (wid >> 1) * 16;              // PV q-subtile
    const int nd = (wid & 1) * 32;               // PV d-subtile

    for (int t = 0; t < 32; ++t) {
        const int cur = t & 1, nxt = cur ^ 1;
        if (t + 1 < 32) {
            const int kb1 = (t + 1) * 64;
            #pragma unroll
            for (int it = 0; it < 2; ++it) {
                int li = it * 256 + tid, row = li >> 3, seg = li & 7;
                GL_LDS16(Kbase + (size_t)(kb1 + row) * DIMD + ((seg ^ (row & 7)) << 3),
                         &Ks[nxt][li * 8]);
            }
            #pragma unroll
            for (int it = 0; it < 2; ++it) {
                int li = it * 256 + tid, row = li >> 3, seg = li & 7;
                GL_LDS16(Vbase + (size_t)row * SEQ + kb1 + ((seg ^ (row & 7)) << 3),
                         &Vs[nxt][li * 8]);
            }
        }
        const int krow = wid * 16 + lr;
        bf16x8 a0 = *(const bf16x8*)(&Ks[cur][krow * 64 + ((hi       ^ (krow & 7)) << 3)]);
        bf16x8 a1 = *(const bf16x8*)(&Ks[cur][krow * 64 + (((4 + hi) ^ (krow & 7)) << 3)]);
        #pragma unroll
        for (int s = 0; s < 2; ++s) {
            f32x4 acc = (f32x4){0.f, 0.f, 0.f, 0.f};
            acc = __builtin_amdgcn_mfma_f32_16x16x32_bf16(a0, qb0[s], acc, 0, 0, 0);
            acc = __builtin_amdgcn_mfma_f32_16x16x32_bf16(a1, qb1[s], acc, 0, 0, 0);
            float e0 = __expf(acc[0] * 0.125f);
            float e1 = __expf(acc[1] * 0.125f);
            float e2 = __expf(acc[2] * 0.125f);
            float e3 = __expf(acc[3] * 0.125f);
            lsum[s] += (e0 + e1) + (e2 + e3);
            usx4 pk;
            pk[0] = f2bf(e0); pk[1] = f2bf(e1); pk[2] = f2bf(e2); pk[3] = f2bf(e3);
            *(usx4*)(&Es[(16 * s + lr) * 68 + wid * 16 + 4 * hi]) = pk;   // Es[q][k_local]
        }
        // bar1: Es visibility only (lgkmcnt), NO vmcnt drain -> prefetch stays in flight
        __builtin_amdgcn_sched_barrier(0);
        asm volatile("s_waitcnt lgkmcnt(0)" ::: "memory");
        __builtin_amdgcn_s_barrier();
        __builtin_amdgcn_sched_barrier(0);

        // PV: wave tile 16q x 32d, K=64 this step
        #pragma unroll
        for (int kk = 0; kk < 2; ++kk) {
            bf16x8 ea = *(const bf16x8*)(&Es[(mq + lr) * 68 + kk * 32 + 8 * hi]);
            #pragma unroll
            for (int j = 0; j < 2; ++j) {
                int vrow = nd + 16 * j + lr;
                int seg = (kk * 4 + hi) ^ (vrow & 7);
                bf16x8 vb = *(const bf16x8*)(&Vs[cur][vrow * 64 + seg * 8]);
                oacc[j] = __builtin_amdgcn_mfma_f32_16x16x32_bf16(ea, vb, oacc[j], 0, 0, 0);
            }
        }
        __syncthreads();   // bar2 (full): WAR fence + vmcnt drain -> next tile ready
    }

    // rowsum reduce -> rl (global for mean_qk, LDS for local scale)
    #pragma unroll
    for (int s = 0; s < 2; ++s) {
        float l = lsum[s];
        l += __shfl_xor(l, 16);
        l += __shfl_xor(l, 32);
        if (lane < 16) ps[wid][s][lane] = l;
    }
    __syncthreads();
    if (tid < 32) {
        int s = tid >> 4, qq = tid & 15;
        float tot = ps[0][s][qq] + ps[1][s][qq] + ps[2][s][qq] + ps[3][s][qq];
        float r = 1.0f / tot;
        rlb[h * SEQ + q0 + 16 * s + qq] = r;
        rls[16 * s + qq] = r;
    }
    __syncthreads();

    #pragma unroll
    for (int r = 0; r < 4; ++r) {
        const int ql = mq + 4 * hi + r;
        const float rv = rls[ql];
        #pragma unroll
        for (int j = 0; j < 2; ++j)
            attn[(size_t)(b * SEQ + q0 + ql) * DIMD + h * HD + nd + 16 * j + lr] =
                f2bf(oacc[j][r] * rv);
    }
}

// ---------------- mean_qk v3 (round-16 BEST-KNOWN): 32 q x 128 k ----------
// out1[q][k] = (1/16) sum_h exp(q.k/8)*rl. Q and K staged via global_load_lds
// (coalesced), dbuf across heads; frags from swizzled ds_read. grid (16,64,2) =
// 2048 blocks = 4 blocks/CU. v4's 64q tile (3 blocks/CU) was ~3 us slower (r18).
__global__ __launch_bounds__(256, 4) void mean_qk_kernel(const unsigned short* __restrict__ Q,
                                                         const unsigned short* __restrict__ Kt,
                                                         const float* __restrict__ rlb_all,
                                                         float* __restrict__ out1_all) {
    __shared__ unsigned short Ks[2][128 * 64];   // 16 KB each
    __shared__ unsigned short Qs[2][32 * 64];    // 4 KB each
    const int tid = threadIdx.x, wid = tid >> 6, lane = tid & 63;
    const int lr = lane & 15, hi = lane >> 4;
    const int b = blockIdx.z;
    const int k0 = blockIdx.x * 128;
    const int q0 = blockIdx.y * 32;
    const unsigned short* Kb2 = Kt + (size_t)b * SEQ * DIMD;
    const unsigned short* Qb2 = Q + (size_t)(b * SEQ + q0) * DIMD;
    const float* rlb = rlb_all + (size_t)b * HEADS * SEQ;
    float* out1b = out1_all + (size_t)b * SEQ * SEQ;

    f32x4 acc[2][2];
    #pragma unroll
    for (int c = 0; c < 2; ++c)
        #pragma unroll
        for (int g = 0; g < 2; ++g) acc[c][g] = (f32x4){0.f, 0.f, 0.f, 0.f};

    // prologue: stage head 0's K (128 rows) + Q (32 rows)
    #pragma unroll
    for (int it = 0; it < 4; ++it) {
        int li = it * 256 + tid, row = li >> 3, seg = li & 7;
        GL_LDS16(Kb2 + (size_t)(k0 + row) * DIMD + ((seg ^ (row & 7)) << 3), &Ks[0][li * 8]);
    }
    {
        int row = tid >> 3, seg = tid & 7;
        GL_LDS16(Qb2 + (size_t)row * DIMD + ((seg ^ (row & 7)) << 3), &Qs[0][tid * 8]);
    }
    __syncthreads();

    for (int h = 0; h < HEADS; ++h) {
        const int cur = h & 1;
        if (h + 1 < HEADS) {                     // prefetch next head's K + Q (overlaps compute)
            const int off2 = (h + 1) * HD;
            #pragma unroll
            for (int it = 0; it < 4; ++it) {
                int li = it * 256 + tid, row = li >> 3, seg = li & 7;
                GL_LDS16(Kb2 + (size_t)(k0 + row) * DIMD + off2 + ((seg ^ (row & 7)) << 3),
                         &Ks[cur ^ 1][li * 8]);
            }
            {
                int row = tid >> 3, seg = tid & 7;
                GL_LDS16(Qb2 + (size_t)row * DIMD + off2 + ((seg ^ (row & 7)) << 3),
                         &Qs[cur ^ 1][tid * 8]);
            }
        }
        // Q frags from LDS (swizzled read) + rl (small, off critical path)
        bf16x8 qb0[2], qb1[2];
        float rlv[2];
        #pragma unroll
        for (int g = 0; g < 2; ++g) {
            const int qrow = 16 * g + lr;
            qb0[g] = *(const bf16x8*)(&Qs[cur][qrow * 64 + ((hi       ^ (qrow & 7)) << 3)]);
            qb1[g] = *(const bf16x8*)(&Qs[cur][qrow * 64 + (((4 + hi) ^ (qrow & 7)) << 3)]);
            rlv[g] = rlb[h * SEQ + q0 + 16 * g + lr] * 0.0625f;   // fold 1/16
        }
        #pragma unroll
        for (int c = 0; c < 2; ++c) {
            const int krow = c * 64 + wid * 16 + lr;
            bf16x8 a0 = *(const bf16x8*)(&Ks[cur][krow * 64 + ((hi       ^ (krow & 7)) << 3)]);
            bf16x8 a1 = *(const bf16x8*)(&Ks[cur][krow * 64 + (((4 + hi) ^ (krow & 7)) << 3)]);
            #pragma unroll
            for (int g = 0; g < 2; ++g) {
                f32x4 s = (f32x4){0.f, 0.f, 0.f, 0.f};
                s = __builtin_amdgcn_mfma_f32_16x16x32_bf16(a0, qb0[g], s, 0, 0, 0);
                s = __builtin_amdgcn_mfma_f32_16x16x32_bf16(a1, qb1[g], s, 0, 0, 0);
                #pragma unroll
                for (int r = 0; r < 4; ++r)
                    acc[c][g][r] += __expf(s[r] * 0.125f) * rlv[g];
            }
        }
        __syncthreads();   // prefetch landed + WAR fence for Ks/Qs[cur]
    }

    // write: q = q0+16g+lr, k = k0 + 64c + 16*wid + 4*hi (f32x4 per (c,g))
    #pragma unroll
    for (int c = 0; c < 2; ++c)
        #pragma unroll
        for (int g = 0; g < 2; ++g)
            *(f32x4*)(out1b + (size_t)(q0 + 16 * g + lr) * SEQ
                              + k0 + 64 * c + 16 * wid + 4 * hi) = acc[c][g];
}

extern "C" void kernel_launch(void* const* d_in, const int* in_sizes, int n_in,
                              void* d_out, int out_size, void* d_ws, size_t ws_size,
                              hipStream_t stream) {
    const float* x  = (const float*)d_in[0];
    const float* wq = (const float*)d_in[1];
    const float* bq = (const float*)d_in[2];
    const float* wk = (const float*)d_in[3];
    const float* bk = (const float*)d_in[4];
    const float* wv = (const float*)d_in[5];
    const float* bv = (const float*)d_in[6];
    const float* wo = (const float*)d_in[7];
    const float* bo = (const float*)d_in[8];

    float* o_out    = (float*)d_out;            // (2,2048,1024)
    float* mean_out = o_out + 4194304;          // (2,2048,2048)

    // workspace layout
    unsigned short* xb   = (unsigned short*)d_ws;
    unsigned short* wqb  = xb   + 4194304;
    unsigned short* wkb  = wqb  + 1048576;
    unsigned short* wvb  = wkb  + 1048576;
    unsigned short* wob  = wvb  + 1048576;
    unsigned short* qb   = wob  + 1048576;
    unsigned short* kb   = qb   + 4194304;
    unsigned short* vTb  = kb   + 4194304;
    unsigned short* attb = vTb  + 4194304;
    float*          rlb  = (float*)(attb + 4194304);
    unsigned short* vb   = (unsigned short*)(rlb + 65536);   // scratch (pre-transpose V)

    cvt_f32_bf16<<<2048, 256, 0, stream>>>(x, xb, 4194304);
    cvt_w4<<<2048, 256, 0, stream>>>(wq, wk, wv, wo, wqb);

    gemm_qkv<<<dim3(24, 32), 256, 0, stream>>>(xb, wqb, bq, bk, bv, qb, kb, vb);
    transpose_v<<<dim3(32, 32), 256, 0, stream>>>(vb, vTb);

    score_pv_kernel<<<dim3(64, 16, 2), 256, 0, stream>>>(qb, kb, vTb, rlb, attb);
    mean_qk_kernel<<<dim3(16, 64, 2), 256, 0, stream>>>(qb, kb, rlb, mean_out);

    gemm_lds<true><<<dim3(16, 32), 256, 0, stream>>>(attb, wob, bo, o_out, DIMD, DIMD);
}

// Round 21
// 186.631 us; speedup vs baseline: 1.0278x; 1.0278x over previous
//
#include <hip/hip_runtime.h>
#include <stdint.h>

#define DIMD 1024
#define HEADS 16
#define HD 64
#define SEQ 2048
#define BATCH 2
#define MTOT (BATCH*SEQ)   // 4096

typedef __attribute__((ext_vector_type(4))) float f32x4;
typedef __attribute__((ext_vector_type(8))) short bf16x8;      // 8 bf16 in 4 VGPRs (MFMA A/B frag)
typedef __attribute__((ext_vector_type(8))) unsigned short ushort8;
typedef __attribute__((ext_vector_type(4))) unsigned short usx4;   // 'ushort4' collides with HIP types
typedef __attribute__((ext_vector_type(2))) unsigned int uix2;

// async global->LDS, 16B per lane; LDS dest must be wave-uniform base + lane*16 (linear)
#define GL_LDS16(gp, lp) __builtin_amdgcn_global_load_lds( \
    (const __attribute__((address_space(1))) unsigned int*)(gp), \
    (__attribute__((address_space(3))) unsigned int*)(lp), 16, 0, 0)

__device__ __forceinline__ unsigned short f2bf(float f) {
    unsigned int u = __builtin_bit_cast(unsigned int, f);
    u = (u + 0x7FFFu + ((u >> 16) & 1u)) >> 16;   // round-to-nearest-even
    return (unsigned short)u;
}
__device__ __forceinline__ float bf2f(unsigned short s) {
    unsigned int u = ((unsigned int)s) << 16;
    return __builtin_bit_cast(float, u);
}
// packed f32x2 -> bf16x2, 1 instr for 2 values (rounding mode: HW-defined)
__device__ __forceinline__ unsigned int cvtpk_bf16(float lo, float hi) {
    unsigned int d;
    asm("v_cvt_pk_bf16_f32 %0, %1, %2" : "=v"(d) : "v"(lo), "v"(hi));
    return d;
}

// ---------------- fp32 -> bf16 convert (8 elems/thread) ----------------
__global__ __launch_bounds__(256) void cvt_f32_bf16(const float* __restrict__ in,
                                                    unsigned short* __restrict__ out, int n) {
    int i = (blockIdx.x * 256 + threadIdx.x) * 8;
    if (i >= n) return;
    f32x4 a = *(const f32x4*)(in + i);
    f32x4 b = *(const f32x4*)(in + i + 4);
    ushort8 o;
    o[0] = f2bf(a[0]); o[1] = f2bf(a[1]); o[2] = f2bf(a[2]); o[3] = f2bf(a[3]);
    o[4] = f2bf(b[0]); o[5] = f2bf(b[1]); o[6] = f2bf(b[2]); o[7] = f2bf(b[3]);
    *(ushort8*)(out + i) = o;
}

// all 4 weight matrices in one launch (dsts are contiguous in ws)
__global__ __launch_bounds__(256) void cvt_w4(const float* __restrict__ w0, const float* __restrict__ w1,
                                              const float* __restrict__ w2, const float* __restrict__ w3,
                                              unsigned short* __restrict__ dst) {
    const int sel = blockIdx.x >> 9;
    const float* src = sel == 0 ? w0 : sel == 1 ? w1 : sel == 2 ? w2 : w3;
    int i = ((blockIdx.x & 511) * 256 + threadIdx.x) * 8;
    f32x4 a = *(const f32x4*)(src + i);
    f32x4 b = *(const f32x4*)(src + i + 4);
    ushort8 o;
    o[0] = f2bf(a[0]); o[1] = f2bf(a[1]); o[2] = f2bf(a[2]); o[3] = f2bf(a[3]);
    o[4] = f2bf(b[0]); o[5] = f2bf(b[1]); o[6] = f2bf(b[2]); o[7] = f2bf(b[3]);
    *(ushort8*)(dst + (size_t)sel * 1048576 + i) = o;
}

// ---------------- LDS-staged GEMM body (tile 128Mx64N, BK=64, dbuf, XOR-swz) ----------
template<bool F32OUT>
__device__ __forceinline__ void gemm_body(const unsigned short* __restrict__ X,
                                          const unsigned short* __restrict__ W,
                                          const float* __restrict__ bias,
                                          void* __restrict__ outp,
                                          int m0, int n0, int Nv, int Kv,
                                          unsigned short (*As)[128 * 64],
                                          unsigned short (*Bs)[64 * 64]) {
    const int tid = threadIdx.x, wid = tid >> 6;
    const int lane = tid & 63, lr = lane & 15, hi = lane >> 4;
    const int mq = (wid >> 1) * 64, nq = (wid & 1) * 32;
    const int NT = Kv >> 6;

    f32x4 acc[4][2];
    #pragma unroll
    for (int i = 0; i < 4; ++i)
        #pragma unroll
        for (int j = 0; j < 2; ++j) acc[i][j] = (f32x4){0.f, 0.f, 0.f, 0.f};

    #pragma unroll
    for (int it = 0; it < 4; ++it) {
        int li = it * 256 + tid, row = li >> 3, seg = li & 7;
        GL_LDS16(X + (size_t)(m0 + row) * Kv + ((seg ^ (row & 7)) << 3), &As[0][li * 8]);
    }
    #pragma unroll
    for (int it = 0; it < 2; ++it) {
        int li = it * 256 + tid, row = li >> 3, seg = li & 7;
        GL_LDS16(W + (size_t)(n0 + row) * Kv + ((seg ^ (row & 7)) << 3), &Bs[0][li * 8]);
    }
    __syncthreads();

    #pragma unroll 2
    for (int t = 0; t < NT; ++t) {
        const int cur = t & 1, nxt = cur ^ 1;
        if (t + 1 < NT) {
            const int k1 = (t + 1) << 6;
            #pragma unroll
            for (int it = 0; it < 4; ++it) {
                int li = it * 256 + tid, row = li >> 3, seg = li & 7;
                GL_LDS16(X + (size_t)(m0 + row) * Kv + k1 + ((seg ^ (row & 7)) << 3),
                         &As[nxt][li * 8]);
            }
            #pragma unroll
            for (int it = 0; it < 2; ++it) {
                int li = it * 256 + tid, row = li >> 3, seg = li & 7;
                GL_LDS16(W + (size_t)(n0 + row) * Kv + k1 + ((seg ^ (row & 7)) << 3),
                         &Bs[nxt][li * 8]);
            }
        }
        #pragma unroll
        for (int kk = 0; kk < 2; ++kk) {
            bf16x8 af[4], bfr[2];
            #pragma unroll
            for (int i = 0; i < 4; ++i) {
                int row = mq + 16 * i + lr;
                int seg = (kk * 4 + hi) ^ (row & 7);
                af[i] = *(const bf16x8*)(&As[cur][row * 64 + seg * 8]);
            }
            #pragma unroll
            for (int j = 0; j < 2; ++j) {
                int row = nq + 16 * j + lr;
                int seg = (kk * 4 + hi) ^ (row & 7);
                bfr[j] = *(const bf16x8*)(&Bs[cur][row * 64 + seg * 8]);
            }
            #pragma unroll
            for (int i = 0; i < 4; ++i)
                #pragma unroll
                for (int j = 0; j < 2; ++j)
                    acc[i][j] = __builtin_amdgcn_mfma_f32_16x16x32_bf16(af[i], bfr[j], acc[i][j], 0, 0, 0);
        }
        __syncthreads();
    }

    #pragma unroll
    for (int j = 0; j < 2; ++j) {
        const int col = n0 + nq + 16 * j + lr;
        const float bv = bias[col];
        #pragma unroll
        for (int i = 0; i < 4; ++i) {
            #pragma unroll
            for (int r = 0; r < 4; ++r) {
                const int row = m0 + mq + 16 * i + 4 * hi + r;
                float v = acc[i][j][r] + bv;
                if (F32OUT) ((float*)outp)[(size_t)row * Nv + col] = v;
                else        ((unsigned short*)outp)[(size_t)row * Nv + col] = f2bf(v);
            }
        }
    }
}

template<bool F32OUT>
__global__ __launch_bounds__(256, 2) void gemm_lds(const unsigned short* __restrict__ X,
                                                   const unsigned short* __restrict__ W,
                                                   const float* __restrict__ bias,
                                                   void* __restrict__ outp,
                                                   int Nv, int Kv) {
    __shared__ unsigned short As[2][128 * 64];
    __shared__ unsigned short Bs[2][64 * 64];
    gemm_body<F32OUT>(X, W, bias, outp, blockIdx.y * 128, blockIdx.x * 64, Nv, Kv, As, Bs);
}

// ---------------- gemm_qkv: 128M x 128N tile ----------------
__global__ __launch_bounds__(256, 2) void gemm_qkv(const unsigned short* __restrict__ X,
                                                   const unsigned short* __restrict__ Wall,
                                                   const float* __restrict__ b0,
                                                   const float* __restrict__ b1,
                                                   const float* __restrict__ b2,
                                                   unsigned short* __restrict__ o0,
                                                   unsigned short* __restrict__ o1,
                                                   unsigned short* __restrict__ o2) {
    __shared__ unsigned short As[2][128 * 64];   // 16 KB each
    __shared__ unsigned short Bs[2][128 * 64];   // 16 KB each
    const int sel = blockIdx.x >> 3;
    const int n0 = (blockIdx.x & 7) * 128;
    const unsigned short* W = Wall + (size_t)sel * 1048576;
    const float* bias = sel == 0 ? b0 : sel == 1 ? b1 : b2;
    unsigned short* out = sel == 0 ? o0 : sel == 1 ? o1 : o2;

    const int tid = threadIdx.x, wid = tid >> 6;
    const int lane = tid & 63, lr = lane & 15, hi = lane >> 4;
    const int m0 = blockIdx.y * 128;
    const int mq = (wid >> 1) * 64, nq = (wid & 1) * 64;

    f32x4 acc[4][4];
    #pragma unroll
    for (int i = 0; i < 4; ++i)
        #pragma unroll
        for (int j = 0; j < 4; ++j) acc[i][j] = (f32x4){0.f, 0.f, 0.f, 0.f};

    #pragma unroll
    for (int it = 0; it < 4; ++it) {
        int li = it * 256 + tid, row = li >> 3, seg = li & 7;
        GL_LDS16(X + (size_t)(m0 + row) * DIMD + ((seg ^ (row & 7)) << 3), &As[0][li * 8]);
    }
    #pragma unroll
    for (int it = 0; it < 4; ++it) {
        int li = it * 256 + tid, row = li >> 3, seg = li & 7;
        GL_LDS16(W + (size_t)(n0 + row) * DIMD + ((seg ^ (row & 7)) << 3), &Bs[0][li * 8]);
    }
    __syncthreads();

    #pragma unroll 2
    for (int t = 0; t < 16; ++t) {               // 1024/64 K-steps
        const int cur = t & 1, nxt = cur ^ 1;
        if (t + 1 < 16) {
            const int k1 = (t + 1) << 6;
            #pragma unroll
            for (int it = 0; it < 4; ++it) {
                int li = it * 256 + tid, row = li >> 3, seg = li & 7;
                GL_LDS16(X + (size_t)(m0 + row) * DIMD + k1 + ((seg ^ (row & 7)) << 3),
                         &As[nxt][li * 8]);
            }
            #pragma unroll
            for (int it = 0; it < 4; ++it) {
                int li = it * 256 + tid, row = li >> 3, seg = li & 7;
                GL_LDS16(W + (size_t)(n0 + row) * DIMD + k1 + ((seg ^ (row & 7)) << 3),
                         &Bs[nxt][li * 8]);
            }
        }
        #pragma unroll
        for (int kk = 0; kk < 2; ++kk) {
            bf16x8 af[4], bfr[4];
            #pragma unroll
            for (int i = 0; i < 4; ++i) {
                int row = mq + 16 * i + lr;
                int seg = (kk * 4 + hi) ^ (row & 7);
                af[i] = *(const bf16x8*)(&As[cur][row * 64 + seg * 8]);
            }
            #pragma unroll
            for (int j = 0; j < 4; ++j) {
                int row = nq + 16 * j + lr;
                int seg = (kk * 4 + hi) ^ (row & 7);
                bfr[j] = *(const bf16x8*)(&Bs[cur][row * 64 + seg * 8]);
            }
            #pragma unroll
            for (int i = 0; i < 4; ++i)
                #pragma unroll
                for (int j = 0; j < 4; ++j)
                    acc[i][j] = __builtin_amdgcn_mfma_f32_16x16x32_bf16(af[i], bfr[j], acc[i][j], 0, 0, 0);
        }
        __syncthreads();
    }

    #pragma unroll
    for (int j = 0; j < 4; ++j) {
        const int col = n0 + nq + 16 * j + lr;
        const float bv = bias[col];
        #pragma unroll
        for (int i = 0; i < 4; ++i) {
            #pragma unroll
            for (int r = 0; r < 4; ++r) {
                const int row = m0 + mq + 16 * i + 4 * hi + r;
                out[(size_t)row * DIMD + col] = f2bf(acc[i][j][r] + bv);
            }
        }
    }
}

// ---------------- V transpose: v[b,s,h*64+d] -> vT[(b*H+h)*64+d][s] ----------------
__global__ __launch_bounds__(256) void transpose_v(const unsigned short* __restrict__ v,
                                                   unsigned short* __restrict__ vT) {
    __shared__ unsigned short tile[64][72];
    const int bh = blockIdx.y;
    const int b = bh >> 4, h = bh & 15;
    const int s0 = blockIdx.x * 64;
    const int t = threadIdx.x;
    #pragma unroll
    for (int it = 0; it < 2; ++it) {
        int li = it * 256 + t;
        int row = li >> 3, c8 = (li & 7) * 8;
        ushort8 val = *(const ushort8*)(v + (size_t)(b * SEQ + s0 + row) * DIMD + h * HD + c8);
        *(ushort8*)&tile[row][c8] = val;
    }
    __syncthreads();
    #pragma unroll
    for (int it = 0; it < 2; ++it) {
        int li = it * 256 + t;
        int d = li >> 3, s8 = (li & 7) * 8;
        ushort8 o;
        #pragma unroll
        for (int j = 0; j < 8; ++j) o[j] = tile[s8 + j][d];
        *(ushort8*)(vT + (size_t)(bh * HD + d) * SEQ + s0 + s8) = o;
    }
}

// ---------------- fused score+PV (r16 structure + cvt_pk w/ CONSISTENT lsum) ---------
// 32 q-rows per block, 4 waves, grid(64,16,2) -> 4 blocks/CU. Per 64-k step:
// prefetch K/V (dbuf, XOR-swz) | QK^T (swapped) -> __expf -> v_cvt_pk_bf16_f32 ->
// Es | bar1 (lgkmcnt-only) | PV | bar2.
// NUMERICS FIX vs round-9 failure: lsum is summed from the ROUNDED bf16 values
// (unpacked from cvt_pk), so O = sum(E_r*V)/sum(E_r) is exactly normalized
// REGARDLESS of cvt_pk's rounding mode — the round-9 bias (unrounded denominator
// vs rounded numerator) cancels by construction. Saves ~12 VALU ops per E-quad
// vs manual RNE f2bf.
__global__ __launch_bounds__(256, 4) void score_pv_kernel(const unsigned short* __restrict__ Q,
                                                          const unsigned short* __restrict__ Kt,
                                                          const unsigned short* __restrict__ vT,
                                                          float* __restrict__ rlb_all,
                                                          unsigned short* __restrict__ attn) {
    __shared__ unsigned short Ks[2][64 * 64];    // 8 KB each
    __shared__ unsigned short Vs[2][64 * 64];    // 8 KB each
    __shared__ unsigned short Es[32 * 68];       // 4.25 KB, pitch 68 -> bank-spread
    __shared__ float ps[4][2][16];
    __shared__ float rls[32];
    const int tid = threadIdx.x, wid = tid >> 6, lane = tid & 63;
    const int lr = lane & 15, hi = lane >> 4;
    const int h = blockIdx.y;
    const int b = blockIdx.z;
    const int q0 = blockIdx.x * 32;
    float* rlb = rlb_all + (size_t)b * HEADS * SEQ;
    const unsigned short* Kbase = Kt + (size_t)b * SEQ * DIMD + h * HD;
    const unsigned short* Vbase = vT + (size_t)(b * HEADS + h) * HD * SEQ;

    const unsigned short* qbase = Q + (size_t)(b * SEQ + q0) * DIMD + h * HD + 8 * hi;
    bf16x8 qb0[2], qb1[2];
    #pragma unroll
    for (int s = 0; s < 2; ++s) {
        const unsigned short* qp = qbase + (size_t)(16 * s + lr) * DIMD;
        qb0[s] = *(const bf16x8*)qp;
        qb1[s] = *(const bf16x8*)(qp + 32);
    }

    #pragma unroll
    for (int it = 0; it < 2; ++it) {
        int li = it * 256 + tid, row = li >> 3, seg = li & 7;
        GL_LDS16(Kbase + (size_t)row * DIMD + ((seg ^ (row & 7)) << 3), &Ks[0][li * 8]);
    }
    #pragma unroll
    for (int it = 0; it < 2; ++it) {
        int li = it * 256 + tid, row = li >> 3, seg = li & 7;
        GL_LDS16(Vbase + (size_t)row * SEQ + ((seg ^ (row & 7)) << 3), &Vs[0][li * 8]);
    }
    __syncthreads();

    float lsum[2] = {0.f, 0.f};
    f32x4 oacc[2];
    oacc[0] = (f32x4){0.f, 0.f, 0.f, 0.f};
    oacc[1] = (f32x4){0.f, 0.f, 0.f, 0.f};
    const int mq = (wid >> 1) * 16;              // PV q-subtile
    const int nd = (wid & 1) * 32;               // PV d-subtile

    for (int t = 0; t < 32; ++t) {
        const int cur = t & 1, nxt = cur ^ 1;
        if (t + 1 < 32) {
            const int kb1 = (t + 1) * 64;
            #pragma unroll
            for (int it = 0; it < 2; ++it) {
                int li = it * 256 + tid, row = li >> 3, seg = li & 7;
                GL_LDS16(Kbase + (size_t)(kb1 + row) * DIMD + ((seg ^ (row & 7)) << 3),
                         &Ks[nxt][li * 8]);
            }
            #pragma unroll
            for (int it = 0; it < 2; ++it) {
                int li = it * 256 + tid, row = li >> 3, seg = li & 7;
                GL_LDS16(Vbase + (size_t)row * SEQ + kb1 + ((seg ^ (row & 7)) << 3),
                         &Vs[nxt][li * 8]);
            }
        }
        const int krow = wid * 16 + lr;
        bf16x8 a0 = *(const bf16x8*)(&Ks[cur][krow * 64 + ((hi       ^ (krow & 7)) << 3)]);
        bf16x8 a1 = *(const bf16x8*)(&Ks[cur][krow * 64 + (((4 + hi) ^ (krow & 7)) << 3)]);
        #pragma unroll
        for (int s = 0; s < 2; ++s) {
            f32x4 acc = (f32x4){0.f, 0.f, 0.f, 0.f};
            acc = __builtin_amdgcn_mfma_f32_16x16x32_bf16(a0, qb0[s], acc, 0, 0, 0);
            acc = __builtin_amdgcn_mfma_f32_16x16x32_bf16(a1, qb1[s], acc, 0, 0, 0);
            float e0 = __expf(acc[0] * 0.125f);
            float e1 = __expf(acc[1] * 0.125f);
            float e2 = __expf(acc[2] * 0.125f);
            float e3 = __expf(acc[3] * 0.125f);
            uix2 pk;
            pk[0] = cvtpk_bf16(e0, e1);
            pk[1] = cvtpk_bf16(e2, e3);
            // lsum from ROUNDED values (consistent with what PV consumes)
            float r0 = __builtin_bit_cast(float, pk[0] << 16);
            float r1 = __builtin_bit_cast(float, pk[0] & 0xFFFF0000u);
            float r2 = __builtin_bit_cast(float, pk[1] << 16);
            float r3 = __builtin_bit_cast(float, pk[1] & 0xFFFF0000u);
            lsum[s] += (r0 + r1) + (r2 + r3);
            *(uix2*)(&Es[(16 * s + lr) * 68 + wid * 16 + 4 * hi]) = pk;   // Es[q][k_local]
        }
        // bar1: Es visibility only (lgkmcnt), NO vmcnt drain -> prefetch stays in flight
        __builtin_amdgcn_sched_barrier(0);
        asm volatile("s_waitcnt lgkmcnt(0)" ::: "memory");
        __builtin_amdgcn_s_barrier();
        __builtin_amdgcn_sched_barrier(0);

        // PV: wave tile 16q x 32d, K=64 this step
        #pragma unroll
        for (int kk = 0; kk < 2; ++kk) {
            bf16x8 ea = *(const bf16x8*)(&Es[(mq + lr) * 68 + kk * 32 + 8 * hi]);
            #pragma unroll
            for (int j = 0; j < 2; ++j) {
                int vrow = nd + 16 * j + lr;
                int seg = (kk * 4 + hi) ^ (vrow & 7);
                bf16x8 vb = *(const bf16x8*)(&Vs[cur][vrow * 64 + seg * 8]);
                oacc[j] = __builtin_amdgcn_mfma_f32_16x16x32_bf16(ea, vb, oacc[j], 0, 0, 0);
            }
        }
        __syncthreads();   // bar2 (full): WAR fence + vmcnt drain -> next tile ready
    }

    // rowsum reduce -> rl (global for mean_qk, LDS for local scale)
    #pragma unroll
    for (int s = 0; s < 2; ++s) {
        float l = lsum[s];
        l += __shfl_xor(l, 16);
        l += __shfl_xor(l, 32);
        if (lane < 16) ps[wid][s][lane] = l;
    }
    __syncthreads();
    if (tid < 32) {
        int s = tid >> 4, qq = tid & 15;
        float tot = ps[0][s][qq] + ps[1][s][qq] + ps[2][s][qq] + ps[3][s][qq];
        float r = 1.0f / tot;
        rlb[h * SEQ + q0 + 16 * s + qq] = r;
        rls[16 * s + qq] = r;
    }
    __syncthreads();

    #pragma unroll
    for (int r = 0; r < 4; ++r) {
        const int ql = mq + 4 * hi + r;
        const float rv = rls[ql];
        #pragma unroll
        for (int j = 0; j < 2; ++j)
            attn[(size_t)(b * SEQ + q0 + ql) * DIMD + h * HD + nd + 16 * j + lr] =
                f2bf(oacc[j][r] * rv);
    }
}

// ---------------- mean_qk v3 (best-known): 32 q x 128 k ----------
__global__ __launch_bounds__(256, 4) void mean_qk_kernel(const unsigned short* __restrict__ Q,
                                                         const unsigned short* __restrict__ Kt,
                                                         const float* __restrict__ rlb_all,
                                                         float* __restrict__ out1_all) {
    __shared__ unsigned short Ks[2][128 * 64];   // 16 KB each
    __shared__ unsigned short Qs[2][32 * 64];    // 4 KB each
    const int tid = threadIdx.x, wid = tid >> 6, lane = tid & 63;
    const int lr = lane & 15, hi = lane >> 4;
    const int b = blockIdx.z;
    const int k0 = blockIdx.x * 128;
    const int q0 = blockIdx.y * 32;
    const unsigned short* Kb2 = Kt + (size_t)b * SEQ * DIMD;
    const unsigned short* Qb2 = Q + (size_t)(b * SEQ + q0) * DIMD;
    const float* rlb = rlb_all + (size_t)b * HEADS * SEQ;
    float* out1b = out1_all + (size_t)b * SEQ * SEQ;

    f32x4 acc[2][2];
    #pragma unroll
    for (int c = 0; c < 2; ++c)
        #pragma unroll
        for (int g = 0; g < 2; ++g) acc[c][g] = (f32x4){0.f, 0.f, 0.f, 0.f};

    // prologue: stage head 0's K (128 rows) + Q (32 rows)
    #pragma unroll
    for (int it = 0; it < 4; ++it) {
        int li = it * 256 + tid, row = li >> 3, seg = li & 7;
        GL_LDS16(Kb2 + (size_t)(k0 + row) * DIMD + ((seg ^ (row & 7)) << 3), &Ks[0][li * 8]);
    }
    {
        int row = tid >> 3, seg = tid & 7;
        GL_LDS16(Qb2 + (size_t)row * DIMD + ((seg ^ (row & 7)) << 3), &Qs[0][tid * 8]);
    }
    __syncthreads();

    for (int h = 0; h < HEADS; ++h) {
        const int cur = h & 1;
        if (h + 1 < HEADS) {                     // prefetch next head's K + Q (overlaps compute)
            const int off2 = (h + 1) * HD;
            #pragma unroll
            for (int it = 0; it < 4; ++it) {
                int li = it * 256 + tid, row = li >> 3, seg = li & 7;
                GL_LDS16(Kb2 + (size_t)(k0 + row) * DIMD + off2 + ((seg ^ (row & 7)) << 3),
                         &Ks[cur ^ 1][li * 8]);
            }
            {
                int row = tid >> 3, seg = tid & 7;
                GL_LDS16(Qb2 + (size_t)row * DIMD + off2 + ((seg ^ (row & 7)) << 3),
                         &Qs[cur ^ 1][tid * 8]);
            }
        }
        // Q frags from LDS (swizzled read) + rl (small, off critical path)
        bf16x8 qb0[2], qb1[2];
        float rlv[2];
        #pragma unroll
        for (int g = 0; g < 2; ++g) {
            const int qrow = 16 * g + lr;
            qb0[g] = *(const bf16x8*)(&Qs[cur][qrow * 64 + ((hi       ^ (qrow & 7)) << 3)]);
            qb1[g] = *(const bf16x8*)(&Qs[cur][qrow * 64 + (((4 + hi) ^ (qrow & 7)) << 3)]);
            rlv[g] = rlb[h * SEQ + q0 + 16 * g + lr] * 0.0625f;   // fold 1/16
        }
        #pragma unroll
        for (int c = 0; c < 2; ++c) {
            const int krow = c * 64 + wid * 16 + lr;
            bf16x8 a0 = *(const bf16x8*)(&Ks[cur][krow * 64 + ((hi       ^ (krow & 7)) << 3)]);
            bf16x8 a1 = *(const bf16x8*)(&Ks[cur][krow * 64 + (((4 + hi) ^ (krow & 7)) << 3)]);
            #pragma unroll
            for (int g = 0; g < 2; ++g) {
                f32x4 s = (f32x4){0.f, 0.f, 0.f, 0.f};
                s = __builtin_amdgcn_mfma_f32_16x16x32_bf16(a0, qb0[g], s, 0, 0, 0);
                s = __builtin_amdgcn_mfma_f32_16x16x32_bf16(a1, qb1[g], s, 0, 0, 0);
                #pragma unroll
                for (int r = 0; r < 4; ++r)
                    acc[c][g][r] += __expf(s[r] * 0.125f) * rlv[g];
            }
        }
        __syncthreads();   // prefetch landed + WAR fence for Ks/Qs[cur]
    }

    // write: q = q0+16g+lr, k = k0 + 64c + 16*wid + 4*hi (f32x4 per (c,g))
    #pragma unroll
    for (int c = 0; c < 2; ++c)
        #pragma unroll
        for (int g = 0; g < 2; ++g)
            *(f32x4*)(out1b + (size_t)(q0 + 16 * g + lr) * SEQ
                              + k0 + 64 * c + 16 * wid + 4 * hi) = acc[c][g];
}

extern "C" void kernel_launch(void* const* d_in, const int* in_sizes, int n_in,
                              void* d_out, int out_size, void* d_ws, size_t ws_size,
                              hipStream_t stream) {
    const float* x  = (const float*)d_in[0];
    const float* wq = (const float*)d_in[1];
    const float* bq = (const float*)d_in[2];
    const float* wk = (const float*)d_in[3];
    const float* bk = (const float*)d_in[4];
    const float* wv = (const float*)d_in[5];
    const float* bv = (const float*)d_in[6];
    const float* wo = (const float*)d_in[7];
    const float* bo = (const float*)d_in[8];

    float* o_out    = (float*)d_out;            // (2,2048,1024)
    float* mean_out = o_out + 4194304;          // (2,2048,2048)

    // workspace layout
    unsigned short* xb   = (unsigned short*)d_ws;
    unsigned short* wqb  = xb   + 4194304;
    unsigned short* wkb  = wqb  + 1048576;
    unsigned short* wvb  = wkb  + 1048576;
    unsigned short* wob  = wvb  + 1048576;
    unsigned short* qb   = wob  + 1048576;
    unsigned short* kb   = qb   + 4194304;
    unsigned short* vTb  = kb   + 4194304;
    unsigned short* attb = vTb  + 4194304;
    float*          rlb  = (float*)(attb + 4194304);
    unsigned short* vb   = (unsigned short*)(rlb + 65536);   // scratch (pre-transpose V)

    cvt_f32_bf16<<<2048, 256, 0, stream>>>(x, xb, 4194304);
    cvt_w4<<<2048, 256, 0, stream>>>(wq, wk, wv, wo, wqb);

    gemm_qkv<<<dim3(24, 32), 256, 0, stream>>>(xb, wqb, bq, bk, bv, qb, kb, vb);
    transpose_v<<<dim3(32, 32), 256, 0, stream>>>(vb, vTb);

    score_pv_kernel<<<dim3(64, 16, 2), 256, 0, stream>>>(qb, kb, vTb, rlb, attb);
    mean_qk_kernel<<<dim3(16, 64, 2), 256, 0, stream>>>(qb, kb, rlb, mean_out);

    gemm_lds<true><<<dim3(16, 32), 256, 0, stream>>>(attb, wob, bo, o_out, DIMD, DIMD);
}